// Round 1
// 949.191 us; speedup vs baseline: 1.0082x; 1.0082x over previous
//
#include <hip/hip_runtime.h>

// MHA forward on MI355X (gfx950). bf16 MFMA compute, f32 accumulate.
// R3: GEMMs upgraded from m97-style 128x128 2-phase to 256x256 8-phase
//     (T2 chunk-XOR LDS swizzle via pre-swizzled global source, T3/T4
//     counted vmcnt, T5 setprio). convert/transpose/attn unchanged.
// B=8, NQ=NK=1024, D_MODEL=1024, H=16, DK=DV=64.

typedef unsigned short u16;
typedef __attribute__((ext_vector_type(8))) short short8;   // 8 bf16 fragment
typedef __attribute__((ext_vector_type(4))) float float4v;  // MFMA C/D fragment

__device__ __forceinline__ u16 f2bf(float f) {
    unsigned int u = __float_as_uint(f);
    u = (u + 0x7fffu + ((u >> 16) & 1u)) >> 16;   // RNE
    return (u16)u;
}

__device__ __forceinline__ void glds16(const void* g, void* l) {
    __builtin_amdgcn_global_load_lds(
        (const __attribute__((address_space(1))) unsigned int*)g,
        (__attribute__((address_space(3))) unsigned int*)l, 16, 0, 0);
}

// raw barrier: no implicit vmcnt/lgkmcnt drain (unlike __syncthreads),
// empty asm = compiler-level memory fence so loads/stores stay in-phase.
__device__ __forceinline__ void bar() {
    asm volatile("" ::: "memory");
    __builtin_amdgcn_s_barrier();
    asm volatile("" ::: "memory");
}

// ---------------------------------------------------------------------------
// f32 -> bf16 pre-cast: q,k,v (8.4M each) + Wq,Wk,Wv,Wo (1M each) into ws.
// ---------------------------------------------------------------------------
__global__ __launch_bounds__(256) void convert_bf16(const float* s0, const float* s1,
                                                    const float* s2, const float* s3,
                                                    const float* s4, const float* s5,
                                                    const float* s6, u16* base) {
    const size_t offs[7] = {0, 8388608, 16777216, 25165824, 26214400, 27262976, 28311552};
    const int    ns[7]   = {8388608, 8388608, 8388608, 1048576, 1048576, 1048576, 1048576};
    const float* srcs[7] = {s0, s1, s2, s3, s4, s5, s6};
    const int t = blockIdx.y;
    const float* src = srcs[t];
    u16* dst = base + offs[t];
    const int n8 = ns[t] >> 3;
    const int stride = gridDim.x * 256;
    for (int i = blockIdx.x * 256 + threadIdx.x; i < n8; i += stride) {
        float4 a = ((const float4*)src)[i * 2];
        float4 b = ((const float4*)src)[i * 2 + 1];
        uint4 o;
        o.x = (unsigned)f2bf(a.x) | ((unsigned)f2bf(a.y) << 16);
        o.y = (unsigned)f2bf(a.z) | ((unsigned)f2bf(a.w) << 16);
        o.z = (unsigned)f2bf(b.x) | ((unsigned)f2bf(b.y) << 16);
        o.w = (unsigned)f2bf(b.z) | ((unsigned)f2bf(b.w) << 16);
        ((uint4*)dst)[i] = o;
    }
}

// ---------------------------------------------------------------------------
// C[M][1024] = A[M][1024] @ W[1024][1024]^T + bias (NT), all-bf16.
// 256x256 tile, BK=64, 8 waves (2M x 4N, 128x64 each), double-buffered
// 128KiB LDS, 4 phases/K-tile, counted vmcnt, chunk-XOR swizzle.
// blockIdx.z selects (A,W,bias,C) instance for fused QKV.
//
// Staging: per K-tile 8 chunks (A0..A3,B0..B3; chunk = 64 rows x 64 bf16 =
// 8KB = one glds16 per 512-thread block). Issue order B0,B1|B2,B3|A0,A2|A1,A3
// across phases 0..3 so:
//   phase-1-end vmcnt(4) -> A1,A3 of CURRENT tile landed (phase 2 reads them)
//   phase-3-end vmcnt(2) -> B0..B3,A0,A2 of NEXT tile landed (phase 0 reads)
// Each vmcnt precedes a barrier, so cross-wave staging completeness holds.
//
// Swizzle: LDS(row, ch) holds global 16B-chunk (ch ^ (row&7)); glds writes
// linearly so the global source col is pre-XOR'd; ds_read applies the same
// XOR -> lanes c=0..15 hit all 8 chunk slots (2 lanes/bank = conflict-free).
// ---------------------------------------------------------------------------
template <bool OUT_BF16>
__global__ __launch_bounds__(512, 2) void gemm_bt8(const u16* __restrict__ Ab,
                                                   const u16* __restrict__ Wb,
                                                   const float* b0, const float* b1,
                                                   const float* b2, void* Cb,
                                                   size_t Astride, size_t Wstride,
                                                   size_t Cstride) {
    __shared__ __align__(16) u16 As[32768];   // 2 slots x 256 rows x 64 bf16
    __shared__ __align__(16) u16 Bs[32768];

    const int z = blockIdx.z;
    const u16* A = Ab + (size_t)z * Astride;
    const u16* W = Wb + (size_t)z * Wstride;
    const float* bias = (z == 0) ? b0 : (z == 1) ? b1 : b2;

    const int m0 = blockIdx.x * 256, n0 = blockIdx.y * 256;
    const int tid = threadIdx.x, lane = tid & 63, ww = tid >> 6;
    const int wm = ww & 1, wn = ww >> 1;               // wave tile: rows wm*128, cols wn*64
    const int c = lane & 15, quad = (lane >> 4) & 3;

    // staging thread map: chunk cc covers tile rows cc*64 .. cc*64+63
    const int srow = tid >> 3;                         // 0..63 row within chunk
    const int scol = ((tid & 7) ^ (srow & 7)) << 3;    // pre-swizzled 16B chunk (u16 units)
    const int wbase = ww << 9;                         // wave's linear LDS u16 offset

    auto stA = [&](int slot, int cc, int kt) {
        glds16(&A[(size_t)(m0 + cc * 64 + srow) * 1024 + kt * 64 + scol],
               &As[slot * 16384 + cc * 4096 + wbase]);
    };
    auto stB = [&](int slot, int cc, int kt) {
        glds16(&W[(size_t)(n0 + cc * 64 + srow) * 1024 + kt * 64 + scol],
               &Bs[slot * 16384 + cc * 4096 + wbase]);
    };
    auto ldA = [&](int slot, int mh, int mi, int ks) -> short8 {
        int row = wm * 128 + mh * 64 + mi * 16 + c;
        int ch = ((ks << 2) + quad) ^ (c & 7);
        return *(const short8*)&As[slot * 16384 + row * 64 + ch * 8];
    };
    auto ldB = [&](int slot, int nh, int ni, int ks) -> short8 {
        int row = wn * 64 + nh * 32 + ni * 16 + c;
        int ch = ((ks << 2) + quad) ^ (c & 7);
        return *(const short8*)&Bs[slot * 16384 + row * 64 + ch * 8];
    };

    float4v acc[8][4] = {};   // [mh*4+mi][nh*2+ni]

    // ---- prologue: tile 0 -> slot 0 (same issue order as steady state) ----
    stB(0, 0, 0); stB(0, 1, 0); stB(0, 2, 0); stB(0, 3, 0);
    stA(0, 0, 0); stA(0, 2, 0); stA(0, 1, 0); stA(0, 3, 0);
    asm volatile("s_waitcnt vmcnt(2)" ::: "memory");   // B0..B3,A0,A2 landed
    bar();

    auto step = [&](int t, int slot, bool pre) {
        const int nxt = slot ^ 1;
        short8 af0[4][2], af1[4][2], bf[2][2][2];
        // ---------- phase 0: quadrant (mh0, nh0) ----------
#pragma unroll
        for (int mi = 0; mi < 4; ++mi)
#pragma unroll
            for (int ks = 0; ks < 2; ++ks) af0[mi][ks] = ldA(slot, 0, mi, ks);
#pragma unroll
        for (int ni = 0; ni < 2; ++ni)
#pragma unroll
            for (int ks = 0; ks < 2; ++ks) bf[0][ni][ks] = ldB(slot, 0, ni, ks);
        if (pre) { stB(nxt, 0, t + 1); stB(nxt, 1, t + 1); }
        bar();
        __builtin_amdgcn_s_setprio(1);
#pragma unroll
        for (int mi = 0; mi < 4; ++mi)
#pragma unroll
            for (int ni = 0; ni < 2; ++ni)
#pragma unroll
                for (int ks = 0; ks < 2; ++ks)
                    acc[mi][ni] = __builtin_amdgcn_mfma_f32_16x16x32_bf16(
                        af0[mi][ks], bf[0][ni][ks], acc[mi][ni], 0, 0, 0);
        __builtin_amdgcn_s_setprio(0);
        bar();
        // ---------- phase 1: quadrant (mh0, nh1) ----------
#pragma unroll
        for (int ni = 0; ni < 2; ++ni)
#pragma unroll
            for (int ks = 0; ks < 2; ++ks) bf[1][ni][ks] = ldB(slot, 1, ni, ks);
        if (pre) { stB(nxt, 2, t + 1); stB(nxt, 3, t + 1); }
        bar();
        __builtin_amdgcn_s_setprio(1);
#pragma unroll
        for (int mi = 0; mi < 4; ++mi)
#pragma unroll
            for (int ni = 0; ni < 2; ++ni)
#pragma unroll
                for (int ks = 0; ks < 2; ++ks)
                    acc[mi][2 + ni] = __builtin_amdgcn_mfma_f32_16x16x32_bf16(
                        af0[mi][ks], bf[1][ni][ks], acc[mi][2 + ni], 0, 0, 0);
        __builtin_amdgcn_s_setprio(0);
        if (pre) { asm volatile("s_waitcnt vmcnt(4)" ::: "memory"); }  // A1,A3 (cur tile)
        else     { asm volatile("s_waitcnt vmcnt(0)" ::: "memory"); }  // tail drain
        bar();
        // ---------- phase 2: quadrant (mh1, nh0) ----------
#pragma unroll
        for (int mi = 0; mi < 4; ++mi)
#pragma unroll
            for (int ks = 0; ks < 2; ++ks) af1[mi][ks] = ldA(slot, 1, mi, ks);
        if (pre) { stA(nxt, 0, t + 1); stA(nxt, 2, t + 1); }
        bar();
        __builtin_amdgcn_s_setprio(1);
#pragma unroll
        for (int mi = 0; mi < 4; ++mi)
#pragma unroll
            for (int ni = 0; ni < 2; ++ni)
#pragma unroll
                for (int ks = 0; ks < 2; ++ks)
                    acc[4 + mi][ni] = __builtin_amdgcn_mfma_f32_16x16x32_bf16(
                        af1[mi][ks], bf[0][ni][ks], acc[4 + mi][ni], 0, 0, 0);
        __builtin_amdgcn_s_setprio(0);
        bar();
        // ---------- phase 3: quadrant (mh1, nh1) ----------
        if (pre) { stA(nxt, 1, t + 1); stA(nxt, 3, t + 1); }
        bar();
        __builtin_amdgcn_s_setprio(1);
#pragma unroll
        for (int mi = 0; mi < 4; ++mi)
#pragma unroll
            for (int ni = 0; ni < 2; ++ni)
#pragma unroll
                for (int ks = 0; ks < 2; ++ks)
                    acc[4 + mi][2 + ni] = __builtin_amdgcn_mfma_f32_16x16x32_bf16(
                        af1[mi][ks], bf[1][ni][ks], acc[4 + mi][2 + ni], 0, 0, 0);
        __builtin_amdgcn_s_setprio(0);
        asm volatile("s_waitcnt vmcnt(2)" ::: "memory");   // next tile B0..B3,A0,A2
        bar();
    };

    // K = 1024 -> 16 tiles; unroll by 2 so LDS slot is compile-time.
    for (int th = 0; th < 8; ++th) {
        step(2 * th, 0, true);
        step(2 * th + 1, 1, th < 7);
    }

    // ---- epilogue: C/D layout col=lane&15, row=quad*4+reg ----
#pragma unroll
    for (int bj = 0; bj < 4; ++bj) {
        int n = n0 + wn * 64 + (bj >> 1) * 32 + (bj & 1) * 16 + c;
        float bv = bias[n];
#pragma unroll
        for (int ai = 0; ai < 8; ++ai) {
            int mb = m0 + wm * 128 + (ai >> 2) * 64 + (ai & 3) * 16 + quad * 4;
#pragma unroll
            for (int r = 0; r < 4; ++r) {
                float v = acc[ai][bj][r] + bv;
                size_t off = (size_t)(mb + r) * 1024 + n;
                if (OUT_BF16) ((u16*)Cb + (size_t)z * Cstride)[off] = f2bf(v);
                else          ((float*)Cb)[off] = v;
            }
        }
    }
}

// ---------------------------------------------------------------------------
// Vt[bh][d][key] = Vb[b*1024+key][h*64+d]
// ---------------------------------------------------------------------------
__global__ __launch_bounds__(256) void transpose_v(const u16* __restrict__ Vb,
                                                   u16* __restrict__ Vt) {
    __shared__ __align__(16) u16 t[64][72];
    const int bh = blockIdx.y, b = bh >> 4, h = bh & 15;
    const int k0 = blockIdx.x * 64;
    const int tid = threadIdx.x;
    {
        int key = tid >> 2, d0 = (tid & 3) << 4;
        const uint4* src = (const uint4*)&Vb[(size_t)(b * 1024 + k0 + key) * 1024 + h * 64 + d0];
        *(uint4*)&t[key][d0]     = src[0];
        *(uint4*)&t[key][d0 + 8] = src[1];
    }
    __syncthreads();
    {
        int d = tid & 63, kg = (tid >> 6) << 4;
        uint4 o[2];
        u16* op = (u16*)o;
#pragma unroll
        for (int i = 0; i < 16; ++i) op[i] = t[kg + i][d];
        uint4* dst = (uint4*)&Vt[((size_t)bh * 64 + d) * 1024 + k0 + kg];
        dst[0] = o[0];
        dst[1] = o[1];
    }
}

// ---------------------------------------------------------------------------
// Flash attention per (b,h): 64-q tile/block, 4 waves x 16 q-rows.
// K/Vt tiles staged in LDS via global_load_lds; weights hoisted; bf16 out.
// ---------------------------------------------------------------------------
__global__ __launch_bounds__(256) void attn_kernel(const u16* __restrict__ Qb,
                                                   const u16* __restrict__ Kb,
                                                   const u16* __restrict__ Vt,
                                                   const float* __restrict__ Wts,
                                                   u16* __restrict__ AO) {
    __shared__ __align__(16) u16 Ks[4096];      // 64 keys x 64 d (128B rows)
    __shared__ __align__(16) u16 Vs[4096];      // 64 d x 64 keys
    __shared__ __align__(16) u16 Pl[4][1024];   // wave-private 16q x 64k

    const int qt = blockIdx.x;
    const int bh = blockIdx.y;
    const int b = bh >> 4, h = bh & 15;
    const int q0 = qt * 64;
    const int tid = threadIdx.x, lane = tid & 63, w = tid >> 6;
    const int c = lane & 15, quad = lane >> 4;
    const int qrow = q0 + w * 16;
    const int srow = tid >> 3, scol = (tid & 7) * 8;

    short8 qf[2];
#pragma unroll
    for (int ks = 0; ks < 2; ++ks)
        qf[ks] = *(const short8*)&Qb[(size_t)(b * 1024 + qrow + c) * 1024 + h * 64 + ks * 32 + quad * 8];

    float m_run[4], l_run[4];
    float4v o[4] = {};
#pragma unroll
    for (int r = 0; r < 4; ++r) { m_run[r] = -1e30f; l_run[r] = 0.f; }

    for (int kt = 0; kt <= qt; ++kt) {
        const int k0 = kt * 64;
        // ---- stage K/Vt tiles (8KB each) ----
#pragma unroll
        for (int i = 0; i < 2; ++i) {
            glds16(&Kb[(size_t)(b * 1024 + k0 + i * 32 + srow) * 1024 + h * 64 + scol],
                   &Ks[i * 2048 + w * 512]);
            glds16(&Vt[((size_t)bh * 64 + i * 32 + srow) * 1024 + k0 + scol],
                   &Vs[i * 2048 + w * 512]);
        }
        // hoist weight loads (independent of LDS staging)
        float wv[4][4];
        const float* wp = &Wts[((size_t)bh * 1024 + (qrow + quad * 4)) * 1024 + k0 + c];
#pragma unroll
        for (int t = 0; t < 4; ++t)
#pragma unroll
            for (int r = 0; r < 4; ++r) wv[t][r] = wp[(size_t)r * 1024 + t * 16];
        __syncthreads();
        // ---- S = Q K^T ----
        float4v s[4] = {};
#pragma unroll
        for (int ks = 0; ks < 2; ++ks)
#pragma unroll
            for (int t = 0; t < 4; ++t) {
                short8 kf = *(const short8*)&Ks[(t * 16 + c) * 64 + ks * 32 + quad * 8];
                s[t] = __builtin_amdgcn_mfma_f32_16x16x32_bf16(qf[ks], kf, s[t], 0, 0, 0);
            }
        // ---- scale*weights + causal mask ----
        const bool diag = (kt == qt);
#pragma unroll
        for (int t = 0; t < 4; ++t)
#pragma unroll
            for (int r = 0; r < 4; ++r) {
                float v = s[t][r] * 0.125f * wv[t][r];
                if (diag && (k0 + t * 16 + c) > (qrow + quad * 4 + r)) v = -1e30f;
                s[t][r] = v;
            }
        // ---- online softmax ----
        float alpha[4];
#pragma unroll
        for (int r = 0; r < 4; ++r) {
            float v = fmaxf(fmaxf(s[0][r], s[1][r]), fmaxf(s[2][r], s[3][r]));
#pragma unroll
            for (int off = 1; off < 16; off <<= 1) v = fmaxf(v, __shfl_xor(v, off, 64));
            float mn = fmaxf(m_run[r], v);
            alpha[r] = __expf(m_run[r] - mn);
            m_run[r] = mn;
        }
#pragma unroll
        for (int r = 0; r < 4; ++r) {
            float sum = 0.f;
#pragma unroll
            for (int t = 0; t < 4; ++t) {
                float p = __expf(s[t][r] - m_run[r]);
                s[t][r] = p;
                sum += p;
            }
#pragma unroll
            for (int off = 1; off < 16; off <<= 1) sum += __shfl_xor(sum, off, 64);
            l_run[r] = l_run[r] * alpha[r] + sum;
        }
        // ---- P: C-layout -> wave-private LDS -> A-layout (same-wave DS ordering) ----
#pragma unroll
        for (int t = 0; t < 4; ++t)
#pragma unroll
            for (int r = 0; r < 4; ++r)
                Pl[w][(quad * 4 + r) * 64 + t * 16 + c] = f2bf(s[t][r]);
        // ---- rescale O, O += P V ----
#pragma unroll
        for (int dt = 0; dt < 4; ++dt)
#pragma unroll
            for (int r = 0; r < 4; ++r) o[dt][r] *= alpha[r];
#pragma unroll
        for (int ks = 0; ks < 2; ++ks) {
            short8 pf = *(const short8*)&Pl[w][c * 64 + ks * 32 + quad * 8];
#pragma unroll
            for (int dt = 0; dt < 4; ++dt) {
                short8 vf = *(const short8*)&Vs[(dt * 16 + c) * 64 + ks * 32 + quad * 8];
                o[dt] = __builtin_amdgcn_mfma_f32_16x16x32_bf16(pf, vf, o[dt], 0, 0, 0);
            }
        }
        __syncthreads();   // protect Ks/Vs restage
    }
    // ---- epilogue: AO bf16 ----
#pragma unroll
    for (int dt = 0; dt < 4; ++dt)
#pragma unroll
        for (int r = 0; r < 4; ++r)
            AO[(size_t)(b * 1024 + qrow + quad * 4 + r) * 1024 + h * 64 + dt * 16 + c] =
                f2bf(o[dt][r] / l_run[r]);
}

// ---------------------------------------------------------------------------
extern "C" void kernel_launch(void* const* d_in, const int* in_sizes, int n_in,
                              void* d_out, int out_size, void* d_ws, size_t ws_size,
                              hipStream_t stream) {
    const float* q  = (const float*)d_in[0];
    const float* k  = (const float*)d_in[1];
    const float* v  = (const float*)d_in[2];
    const float* aw = (const float*)d_in[3];
    // d_in[4] = attention_mask (fixed strict-upper causal; computed analytically)
    const float* bq = (const float*)d_in[6];
    const float* bk = (const float*)d_in[8];
    const float* bv = (const float*)d_in[10];
    const float* Wo = (const float*)d_in[11];
    const float* bo = (const float*)d_in[12];
    const float* Wq = (const float*)d_in[5];
    const float* Wk = (const float*)d_in[7];
    const float* Wv = (const float*)d_in[9];

    u16* ws16 = (u16*)d_ws;
    u16* qkvbf = ws16;                   // q,k,v bf16: 3 x 8388608
    u16* Wbf   = ws16 + 25165824;        // Wq,Wk,Wv,Wo bf16: 4 x 1048576
    u16* Wob   = ws16 + 28311552;
    u16* Qb    = ws16 + 29360128;        // Q,K,V projections: 3 x 8388608
    u16* Kb    = Qb + 8388608;
    u16* Vb    = Kb + 8388608;
    u16* Vt    = Vb + 8388608;           // [bh][64][1024]
    u16* AObf  = Vt + 8388608;           // attn output bf16

    dim3 blk(256);
    convert_bf16<<<dim3(512, 7), blk, 0, stream>>>(q, k, v, Wq, Wk, Wv, Wo, ws16);
    gemm_bt8<true><<<dim3(32, 4, 3), dim3(512), 0, stream>>>(qkvbf, Wbf, bq, bk, bv, Qb,
                                                             8388608, 1048576, 8388608);
    transpose_v<<<dim3(16, 128), blk, 0, stream>>>(Vb, Vt);
    attn_kernel<<<dim3(16, 128), blk, 0, stream>>>(Qb, Kb, Vt, aw, AObf);
    gemm_bt8<false><<<dim3(32, 4, 1), dim3(512), 0, stream>>>(AObf, Wob, bo, bo, bo, d_out,
                                                              0, 0, 0);
}

// Round 2
// 940.634 us; speedup vs baseline: 1.0174x; 1.0091x over previous
//
#include <hip/hip_runtime.h>

// MHA forward on MI355X (gfx950). bf16 MFMA compute, f32 accumulate.
// R4: attn LDS bank-conflict fix — T2 chunk-XOR swizzle on Ks/Vs/Pl
//     (pre-swizzled global source for glds16 per rule #21; same XOR on
//     ds_read). GEMMs (R3 8-phase 256x256), convert, transpose unchanged.
// B=8, NQ=NK=1024, D_MODEL=1024, H=16, DK=DV=64.

typedef unsigned short u16;
typedef __attribute__((ext_vector_type(8))) short short8;   // 8 bf16 fragment
typedef __attribute__((ext_vector_type(4))) float float4v;  // MFMA C/D fragment

__device__ __forceinline__ u16 f2bf(float f) {
    unsigned int u = __float_as_uint(f);
    u = (u + 0x7fffu + ((u >> 16) & 1u)) >> 16;   // RNE
    return (u16)u;
}

__device__ __forceinline__ void glds16(const void* g, void* l) {
    __builtin_amdgcn_global_load_lds(
        (const __attribute__((address_space(1))) unsigned int*)g,
        (__attribute__((address_space(3))) unsigned int*)l, 16, 0, 0);
}

// raw barrier: no implicit vmcnt/lgkmcnt drain (unlike __syncthreads),
// empty asm = compiler-level memory fence so loads/stores stay in-phase.
__device__ __forceinline__ void bar() {
    asm volatile("" ::: "memory");
    __builtin_amdgcn_s_barrier();
    asm volatile("" ::: "memory");
}

// ---------------------------------------------------------------------------
// f32 -> bf16 pre-cast: q,k,v (8.4M each) + Wq,Wk,Wv,Wo (1M each) into ws.
// ---------------------------------------------------------------------------
__global__ __launch_bounds__(256) void convert_bf16(const float* s0, const float* s1,
                                                    const float* s2, const float* s3,
                                                    const float* s4, const float* s5,
                                                    const float* s6, u16* base) {
    const size_t offs[7] = {0, 8388608, 16777216, 25165824, 26214400, 27262976, 28311552};
    const int    ns[7]   = {8388608, 8388608, 8388608, 1048576, 1048576, 1048576, 1048576};
    const float* srcs[7] = {s0, s1, s2, s3, s4, s5, s6};
    const int t = blockIdx.y;
    const float* src = srcs[t];
    u16* dst = base + offs[t];
    const int n8 = ns[t] >> 3;
    const int stride = gridDim.x * 256;
    for (int i = blockIdx.x * 256 + threadIdx.x; i < n8; i += stride) {
        float4 a = ((const float4*)src)[i * 2];
        float4 b = ((const float4*)src)[i * 2 + 1];
        uint4 o;
        o.x = (unsigned)f2bf(a.x) | ((unsigned)f2bf(a.y) << 16);
        o.y = (unsigned)f2bf(a.z) | ((unsigned)f2bf(a.w) << 16);
        o.z = (unsigned)f2bf(b.x) | ((unsigned)f2bf(b.y) << 16);
        o.w = (unsigned)f2bf(b.z) | ((unsigned)f2bf(b.w) << 16);
        ((uint4*)dst)[i] = o;
    }
}

// ---------------------------------------------------------------------------
// C[M][1024] = A[M][1024] @ W[1024][1024]^T + bias (NT), all-bf16.
// 256x256 tile, BK=64, 8 waves (2M x 4N, 128x64 each), double-buffered
// 128KiB LDS, 4 phases/K-tile, counted vmcnt, chunk-XOR swizzle.
// blockIdx.z selects (A,W,bias,C) instance for fused QKV.
// ---------------------------------------------------------------------------
template <bool OUT_BF16>
__global__ __launch_bounds__(512, 2) void gemm_bt8(const u16* __restrict__ Ab,
                                                   const u16* __restrict__ Wb,
                                                   const float* b0, const float* b1,
                                                   const float* b2, void* Cb,
                                                   size_t Astride, size_t Wstride,
                                                   size_t Cstride) {
    __shared__ __align__(16) u16 As[32768];   // 2 slots x 256 rows x 64 bf16
    __shared__ __align__(16) u16 Bs[32768];

    const int z = blockIdx.z;
    const u16* A = Ab + (size_t)z * Astride;
    const u16* W = Wb + (size_t)z * Wstride;
    const float* bias = (z == 0) ? b0 : (z == 1) ? b1 : b2;

    const int m0 = blockIdx.x * 256, n0 = blockIdx.y * 256;
    const int tid = threadIdx.x, lane = tid & 63, ww = tid >> 6;
    const int wm = ww & 1, wn = ww >> 1;               // wave tile: rows wm*128, cols wn*64
    const int c = lane & 15, quad = (lane >> 4) & 3;

    // staging thread map: chunk cc covers tile rows cc*64 .. cc*64+63
    const int srow = tid >> 3;                         // 0..63 row within chunk
    const int scol = ((tid & 7) ^ (srow & 7)) << 3;    // pre-swizzled 16B chunk (u16 units)
    const int wbase = ww << 9;                         // wave's linear LDS u16 offset

    auto stA = [&](int slot, int cc, int kt) {
        glds16(&A[(size_t)(m0 + cc * 64 + srow) * 1024 + kt * 64 + scol],
               &As[slot * 16384 + cc * 4096 + wbase]);
    };
    auto stB = [&](int slot, int cc, int kt) {
        glds16(&W[(size_t)(n0 + cc * 64 + srow) * 1024 + kt * 64 + scol],
               &Bs[slot * 16384 + cc * 4096 + wbase]);
    };
    auto ldA = [&](int slot, int mh, int mi, int ks) -> short8 {
        int row = wm * 128 + mh * 64 + mi * 16 + c;
        int ch = ((ks << 2) + quad) ^ (c & 7);
        return *(const short8*)&As[slot * 16384 + row * 64 + ch * 8];
    };
    auto ldB = [&](int slot, int nh, int ni, int ks) -> short8 {
        int row = wn * 64 + nh * 32 + ni * 16 + c;
        int ch = ((ks << 2) + quad) ^ (c & 7);
        return *(const short8*)&Bs[slot * 16384 + row * 64 + ch * 8];
    };

    float4v acc[8][4] = {};   // [mh*4+mi][nh*2+ni]

    // ---- prologue: tile 0 -> slot 0 (same issue order as steady state) ----
    stB(0, 0, 0); stB(0, 1, 0); stB(0, 2, 0); stB(0, 3, 0);
    stA(0, 0, 0); stA(0, 2, 0); stA(0, 1, 0); stA(0, 3, 0);
    asm volatile("s_waitcnt vmcnt(2)" ::: "memory");   // B0..B3,A0,A2 landed
    bar();

    auto step = [&](int t, int slot, bool pre) {
        const int nxt = slot ^ 1;
        short8 af0[4][2], af1[4][2], bf[2][2][2];
        // ---------- phase 0: quadrant (mh0, nh0) ----------
#pragma unroll
        for (int mi = 0; mi < 4; ++mi)
#pragma unroll
            for (int ks = 0; ks < 2; ++ks) af0[mi][ks] = ldA(slot, 0, mi, ks);
#pragma unroll
        for (int ni = 0; ni < 2; ++ni)
#pragma unroll
            for (int ks = 0; ks < 2; ++ks) bf[0][ni][ks] = ldB(slot, 0, ni, ks);
        if (pre) { stB(nxt, 0, t + 1); stB(nxt, 1, t + 1); }
        bar();
        __builtin_amdgcn_s_setprio(1);
#pragma unroll
        for (int mi = 0; mi < 4; ++mi)
#pragma unroll
            for (int ni = 0; ni < 2; ++ni)
#pragma unroll
                for (int ks = 0; ks < 2; ++ks)
                    acc[mi][ni] = __builtin_amdgcn_mfma_f32_16x16x32_bf16(
                        af0[mi][ks], bf[0][ni][ks], acc[mi][ni], 0, 0, 0);
        __builtin_amdgcn_s_setprio(0);
        bar();
        // ---------- phase 1: quadrant (mh0, nh1) ----------
#pragma unroll
        for (int ni = 0; ni < 2; ++ni)
#pragma unroll
            for (int ks = 0; ks < 2; ++ks) bf[1][ni][ks] = ldB(slot, 1, ni, ks);
        if (pre) { stB(nxt, 2, t + 1); stB(nxt, 3, t + 1); }
        bar();
        __builtin_amdgcn_s_setprio(1);
#pragma unroll
        for (int mi = 0; mi < 4; ++mi)
#pragma unroll
            for (int ni = 0; ni < 2; ++ni)
#pragma unroll
                for (int ks = 0; ks < 2; ++ks)
                    acc[mi][2 + ni] = __builtin_amdgcn_mfma_f32_16x16x32_bf16(
                        af0[mi][ks], bf[1][ni][ks], acc[mi][2 + ni], 0, 0, 0);
        __builtin_amdgcn_s_setprio(0);
        if (pre) { asm volatile("s_waitcnt vmcnt(4)" ::: "memory"); }  // A1,A3 (cur tile)
        else     { asm volatile("s_waitcnt vmcnt(0)" ::: "memory"); }  // tail drain
        bar();
        // ---------- phase 2: quadrant (mh1, nh0) ----------
#pragma unroll
        for (int mi = 0; mi < 4; ++mi)
#pragma unroll
            for (int ks = 0; ks < 2; ++ks) af1[mi][ks] = ldA(slot, 1, mi, ks);
        if (pre) { stA(nxt, 0, t + 1); stA(nxt, 2, t + 1); }
        bar();
        __builtin_amdgcn_s_setprio(1);
#pragma unroll
        for (int mi = 0; mi < 4; ++mi)
#pragma unroll
            for (int ni = 0; ni < 2; ++ni)
#pragma unroll
                for (int ks = 0; ks < 2; ++ks)
                    acc[4 + mi][ni] = __builtin_amdgcn_mfma_f32_16x16x32_bf16(
                        af1[mi][ks], bf[0][ni][ks], acc[4 + mi][ni], 0, 0, 0);
        __builtin_amdgcn_s_setprio(0);
        bar();
        // ---------- phase 3: quadrant (mh1, nh1) ----------
        if (pre) { stA(nxt, 1, t + 1); stA(nxt, 3, t + 1); }
        bar();
        __builtin_amdgcn_s_setprio(1);
#pragma unroll
        for (int mi = 0; mi < 4; ++mi)
#pragma unroll
            for (int ni = 0; ni < 2; ++ni)
#pragma unroll
                for (int ks = 0; ks < 2; ++ks)
                    acc[4 + mi][2 + ni] = __builtin_amdgcn_mfma_f32_16x16x32_bf16(
                        af1[mi][ks], bf[1][ni][ks], acc[4 + mi][2 + ni], 0, 0, 0);
        __builtin_amdgcn_s_setprio(0);
        asm volatile("s_waitcnt vmcnt(2)" ::: "memory");   // next tile B0..B3,A0,A2
        bar();
    };

    // K = 1024 -> 16 tiles; unroll by 2 so LDS slot is compile-time.
    for (int th = 0; th < 8; ++th) {
        step(2 * th, 0, true);
        step(2 * th + 1, 1, th < 7);
    }

    // ---- epilogue: C/D layout col=lane&15, row=quad*4+reg ----
#pragma unroll
    for (int bj = 0; bj < 4; ++bj) {
        int n = n0 + wn * 64 + (bj >> 1) * 32 + (bj & 1) * 16 + c;
        float bv = bias[n];
#pragma unroll
        for (int ai = 0; ai < 8; ++ai) {
            int mb = m0 + wm * 128 + (ai >> 2) * 64 + (ai & 3) * 16 + quad * 4;
#pragma unroll
            for (int r = 0; r < 4; ++r) {
                float v = acc[ai][bj][r] + bv;
                size_t off = (size_t)(mb + r) * 1024 + n;
                if (OUT_BF16) ((u16*)Cb + (size_t)z * Cstride)[off] = f2bf(v);
                else          ((float*)Cb)[off] = v;
            }
        }
    }
}

// ---------------------------------------------------------------------------
// Vt[bh][d][key] = Vb[b*1024+key][h*64+d]
// ---------------------------------------------------------------------------
__global__ __launch_bounds__(256) void transpose_v(const u16* __restrict__ Vb,
                                                   u16* __restrict__ Vt) {
    __shared__ __align__(16) u16 t[64][72];
    const int bh = blockIdx.y, b = bh >> 4, h = bh & 15;
    const int k0 = blockIdx.x * 64;
    const int tid = threadIdx.x;
    {
        int key = tid >> 2, d0 = (tid & 3) << 4;
        const uint4* src = (const uint4*)&Vb[(size_t)(b * 1024 + k0 + key) * 1024 + h * 64 + d0];
        *(uint4*)&t[key][d0]     = src[0];
        *(uint4*)&t[key][d0 + 8] = src[1];
    }
    __syncthreads();
    {
        int d = tid & 63, kg = (tid >> 6) << 4;
        uint4 o[2];
        u16* op = (u16*)o;
#pragma unroll
        for (int i = 0; i < 16; ++i) op[i] = t[kg + i][d];
        uint4* dst = (uint4*)&Vt[((size_t)bh * 64 + d) * 1024 + k0 + kg];
        dst[0] = o[0];
        dst[1] = o[1];
    }
}

// ---------------------------------------------------------------------------
// Flash attention per (b,h): 64-q tile/block, 4 waves x 16 q-rows.
// K/Vt tiles staged in LDS via global_load_lds; weights hoisted; bf16 out.
// R4: Ks/Vs/Pl chunk-XOR swizzled (chunk ^= row&7 within each 128B row).
//     glds16 writes linearly -> global source col pre-XOR'd (rule #21);
//     ds_read applies the same XOR. Lanes of each service group now hit
//     8 distinct 16B bank groups (was: all on one bank, 8-way serialize).
// ---------------------------------------------------------------------------
__global__ __launch_bounds__(256) void attn_kernel(const u16* __restrict__ Qb,
                                                   const u16* __restrict__ Kb,
                                                   const u16* __restrict__ Vt,
                                                   const float* __restrict__ Wts,
                                                   u16* __restrict__ AO) {
    __shared__ __align__(16) u16 Ks[4096];      // 64 keys x 64 d (swizzled rows)
    __shared__ __align__(16) u16 Vs[4096];      // 64 d x 64 keys (swizzled rows)
    __shared__ __align__(16) u16 Pl[4][1024];   // wave-private 16q x 64k (swizzled)

    const int qt = blockIdx.x;
    const int bh = blockIdx.y;
    const int b = bh >> 4, h = bh & 15;
    const int q0 = qt * 64;
    const int tid = threadIdx.x, lane = tid & 63, w = tid >> 6;
    const int c = lane & 15, quad = lane >> 4;
    const int qrow = q0 + w * 16;
    const int srow = tid >> 3;
    const int scol = ((tid & 7) ^ (srow & 7)) * 8;   // pre-swizzled source chunk

    short8 qf[2];
#pragma unroll
    for (int ks = 0; ks < 2; ++ks)
        qf[ks] = *(const short8*)&Qb[(size_t)(b * 1024 + qrow + c) * 1024 + h * 64 + ks * 32 + quad * 8];

    float m_run[4], l_run[4];
    float4v o[4] = {};
#pragma unroll
    for (int r = 0; r < 4; ++r) { m_run[r] = -1e30f; l_run[r] = 0.f; }

    for (int kt = 0; kt <= qt; ++kt) {
        const int k0 = kt * 64;
        // ---- stage K/Vt tiles (8KB each), source pre-swizzled ----
#pragma unroll
        for (int i = 0; i < 2; ++i) {
            glds16(&Kb[(size_t)(b * 1024 + k0 + i * 32 + srow) * 1024 + h * 64 + scol],
                   &Ks[i * 2048 + w * 512]);
            glds16(&Vt[((size_t)bh * 64 + i * 32 + srow) * 1024 + k0 + scol],
                   &Vs[i * 2048 + w * 512]);
        }
        // hoist weight loads (independent of LDS staging)
        float wv[4][4];
        const float* wp = &Wts[((size_t)bh * 1024 + (qrow + quad * 4)) * 1024 + k0 + c];
#pragma unroll
        for (int t = 0; t < 4; ++t)
#pragma unroll
            for (int r = 0; r < 4; ++r) wv[t][r] = wp[(size_t)r * 1024 + t * 16];
        __syncthreads();
        // ---- S = Q K^T ----
        float4v s[4] = {};
#pragma unroll
        for (int ks = 0; ks < 2; ++ks)
#pragma unroll
            for (int t = 0; t < 4; ++t) {
                short8 kf = *(const short8*)&Ks[(t * 16 + c) * 64 +
                                                ((((ks << 2) + quad) ^ (c & 7)) << 3)];
                s[t] = __builtin_amdgcn_mfma_f32_16x16x32_bf16(qf[ks], kf, s[t], 0, 0, 0);
            }
        // ---- scale*weights + causal mask ----
        const bool diag = (kt == qt);
#pragma unroll
        for (int t = 0; t < 4; ++t)
#pragma unroll
            for (int r = 0; r < 4; ++r) {
                float v = s[t][r] * 0.125f * wv[t][r];
                if (diag && (k0 + t * 16 + c) > (qrow + quad * 4 + r)) v = -1e30f;
                s[t][r] = v;
            }
        // ---- online softmax ----
        float alpha[4];
#pragma unroll
        for (int r = 0; r < 4; ++r) {
            float v = fmaxf(fmaxf(s[0][r], s[1][r]), fmaxf(s[2][r], s[3][r]));
#pragma unroll
            for (int off = 1; off < 16; off <<= 1) v = fmaxf(v, __shfl_xor(v, off, 64));
            float mn = fmaxf(m_run[r], v);
            alpha[r] = __expf(m_run[r] - mn);
            m_run[r] = mn;
        }
#pragma unroll
        for (int r = 0; r < 4; ++r) {
            float sum = 0.f;
#pragma unroll
            for (int t = 0; t < 4; ++t) {
                float p = __expf(s[t][r] - m_run[r]);
                s[t][r] = p;
                sum += p;
            }
#pragma unroll
            for (int off = 1; off < 16; off <<= 1) sum += __shfl_xor(sum, off, 64);
            l_run[r] = l_run[r] * alpha[r] + sum;
        }
        // ---- P: C-layout -> wave-private LDS (swizzled) -> A-layout ----
#pragma unroll
        for (int t = 0; t < 4; ++t)
#pragma unroll
            for (int r = 0; r < 4; ++r) {
                int row = quad * 4 + r;
                int col = (((t * 2 + (c >> 3)) ^ (row & 7)) << 3) + (c & 7);
                Pl[w][row * 64 + col] = f2bf(s[t][r]);
            }
        // ---- rescale O, O += P V ----
#pragma unroll
        for (int dt = 0; dt < 4; ++dt)
#pragma unroll
            for (int r = 0; r < 4; ++r) o[dt][r] *= alpha[r];
#pragma unroll
        for (int ks = 0; ks < 2; ++ks) {
            short8 pf = *(const short8*)&Pl[w][c * 64 +
                                              ((((ks << 2) + quad) ^ (c & 7)) << 3)];
#pragma unroll
            for (int dt = 0; dt < 4; ++dt) {
                short8 vf = *(const short8*)&Vs[(dt * 16 + c) * 64 +
                                                ((((ks << 2) + quad) ^ (c & 7)) << 3)];
                o[dt] = __builtin_amdgcn_mfma_f32_16x16x32_bf16(pf, vf, o[dt], 0, 0, 0);
            }
        }
        __syncthreads();   // protect Ks/Vs restage
    }
    // ---- epilogue: AO bf16 ----
#pragma unroll
    for (int dt = 0; dt < 4; ++dt)
#pragma unroll
        for (int r = 0; r < 4; ++r)
            AO[(size_t)(b * 1024 + qrow + quad * 4 + r) * 1024 + h * 64 + dt * 16 + c] =
                f2bf(o[dt][r] / l_run[r]);
}

// ---------------------------------------------------------------------------
extern "C" void kernel_launch(void* const* d_in, const int* in_sizes, int n_in,
                              void* d_out, int out_size, void* d_ws, size_t ws_size,
                              hipStream_t stream) {
    const float* q  = (const float*)d_in[0];
    const float* k  = (const float*)d_in[1];
    const float* v  = (const float*)d_in[2];
    const float* aw = (const float*)d_in[3];
    // d_in[4] = attention_mask (fixed strict-upper causal; computed analytically)
    const float* bq = (const float*)d_in[6];
    const float* bk = (const float*)d_in[8];
    const float* bv = (const float*)d_in[10];
    const float* Wo = (const float*)d_in[11];
    const float* bo = (const float*)d_in[12];
    const float* Wq = (const float*)d_in[5];
    const float* Wk = (const float*)d_in[7];
    const float* Wv = (const float*)d_in[9];

    u16* ws16 = (u16*)d_ws;
    u16* qkvbf = ws16;                   // q,k,v bf16: 3 x 8388608
    u16* Wbf   = ws16 + 25165824;        // Wq,Wk,Wv,Wo bf16: 4 x 1048576
    u16* Wob   = ws16 + 28311552;
    u16* Qb    = ws16 + 29360128;        // Q,K,V projections: 3 x 8388608
    u16* Kb    = Qb + 8388608;
    u16* Vb    = Kb + 8388608;
    u16* Vt    = Vb + 8388608;           // [bh][64][1024]
    u16* AObf  = Vt + 8388608;           // attn output bf16

    dim3 blk(256);
    convert_bf16<<<dim3(512, 7), blk, 0, stream>>>(q, k, v, Wq, Wk, Wv, Wo, ws16);
    gemm_bt8<true><<<dim3(32, 4, 3), dim3(512), 0, stream>>>(qkvbf, Wbf, bq, bk, bv, Qb,
                                                             8388608, 1048576, 8388608);
    transpose_v<<<dim3(16, 128), blk, 0, stream>>>(Vb, Vt);
    attn_kernel<<<dim3(16, 128), blk, 0, stream>>>(Qb, Kb, Vt, aw, AObf);
    gemm_bt8<false><<<dim3(32, 4, 1), dim3(512), 0, stream>>>(AObf, Wob, bo, bo, bo, d_out,
                                                              0, 0, 0);
}